// Round 11
// baseline (291.580 us; speedup 1.0000x reference)
//
#include <hip/hip_runtime.h>
#include <hip/hip_cooperative_groups.h>
#include <math.h>

namespace cg = cooperative_groups;

#define B_   16
#define N_   1024
#define DIM_ 128
#define H_   8
#define D_   16
#define BH_  128

typedef unsigned short u16;
typedef unsigned int   u32;
typedef __attribute__((ext_vector_type(8))) short short8;
typedef __attribute__((ext_vector_type(4))) float f32x4;

__device__ __forceinline__ float bf2f(u16 u) {
    union { u32 i; float f; } c; c.i = ((u32)u) << 16; return c.f;
}
__device__ __forceinline__ u16 f2bf(float f) {
    union { float f; u32 i; } c; c.f = f;
    u32 r = c.i + 0x7FFFu + ((c.i >> 16) & 1u);
    return (u16)(r >> 16);
}
// pack two f32 -> packed bf16 pair (round-half-up on magnitude)
__device__ __forceinline__ u32 pack2bf(float a, float b) {
    union { float f; u32 i; } ca, cb; ca.f = a; cb.f = b;
    return ((ca.i + 0x8000u) >> 16) | ((cb.i + 0x8000u) & 0xFFFF0000u);
}
union frag8 { short8 s; u32 w[4]; };

#define BF_ONE  ((short)0x3F80)
#define BF_NINF ((u16)0xFF80)
#define SCALE_L2E (0.08838834764831845f * 1.4426950408889634f)

#define MFMA16 __builtin_amdgcn_mfma_f32_16x16x32_bf16

// ==================== FUSED cooperative pipeline ====================
// P0: Wqkv/Wout -> bf16 transposed [col][k].   grid.sync()
// P1: qkv GEMM (x converted in-register, A-frags reused across 3 col-blocks),
//     scatter Q (pre-scaled), K2 (32-wide rows + bias slot 16), Vt.  sync()
// P2: attention (4 q-tiles/wave, bias-in-K, no-max exp2 softmax).    sync()
// P3: out GEMM + bias -> d_out (f32).
__global__ __launch_bounds__(256) void fused_kernel(
    const float* __restrict__ x, const float* __restrict__ maskp,
    const float* __restrict__ mapsp, const float* __restrict__ Wqkv,
    const float* __restrict__ Wout, const float* __restrict__ boutp,
    u16* __restrict__ qws, u16* __restrict__ kws2, u16* __restrict__ vtws,
    u16* __restrict__ attnw, u16* __restrict__ wqkvb, u16* __restrict__ woutb,
    float* __restrict__ outp)
{
    cg::grid_group grid = cg::this_grid();
    const int blk  = blockIdx.x;           // 0..511
    const int tid  = threadIdx.x;
    const int wave = tid >> 6, lane = tid & 63;
    const int i16  = lane & 15, quad = lane >> 4;

    // ---------- P0: weight conversion + transpose ----------
    {
        const int t = blk * 256 + tid;
        if (t < 49152) {                    // Wqkv[k][col] -> wqkvb[col][k]
            const int k = t / 384, col = t - k * 384;
            wqkvb[(size_t)col * 128 + k] = f2bf(Wqkv[t]);
        } else if (t < 65536) {             // Wout[k][col] -> woutb[col][k]
            const int t2 = t - 49152;
            const int k = t2 >> 7, col = t2 & 127;
            woutb[(size_t)col * 128 + k] = f2bf(Wout[t2]);
        }
    }
    grid.sync();

    // ---------- P1: qkv ----------
    {
        const int rb  = blk >> 1;              // 0..255 (64-row block)
        const int cb0 = (blk & 1) * 3;         // col-blocks {0,1,2} or {3,4,5}
        const int row_m = rb * 64 + wave * 16;
        const float* xp = x + (size_t)(row_m + i16) * 128;

        // A-frags: x row (f32) -> 4 bf16 frags, loaded once, reused for 3 cb
        short8 a0, a1, a2, a3;
        #define LOADA(A, K0) { \
            const int k0 = (K0) + quad * 8; \
            const float4 xa = *(const float4*)(xp + k0); \
            const float4 xb2 = *(const float4*)(xp + k0 + 4); \
            frag8 t_; \
            t_.w[0] = pack2bf(xa.x, xa.y); t_.w[1] = pack2bf(xa.z, xa.w); \
            t_.w[2] = pack2bf(xb2.x, xb2.y); t_.w[3] = pack2bf(xb2.z, xb2.w); \
            A = t_.s; }
        LOADA(a0, 0) LOADA(a1, 32) LOADA(a2, 64) LOADA(a3, 96)
        #undef LOADA

        const int row = row_m + quad * 4;
        const int bb  = row >> 10, n = row & 1023;

        for (int ci = 0; ci < 3; ci++) {
            const int cb = cb0 + ci;
            const u16* wb = wqkvb + (size_t)(cb * 64 + i16) * 128;
            f32x4 acc0 = {0,0,0,0}, acc1 = {0,0,0,0}, acc2 = {0,0,0,0}, acc3 = {0,0,0,0};
            #define KSTEP(A, K0) { \
                const int k0 = (K0) + quad * 8; \
                acc0 = MFMA16(A, *(const short8*)(wb + k0),            acc0, 0,0,0); \
                acc1 = MFMA16(A, *(const short8*)(wb + 16*128 + k0),   acc1, 0,0,0); \
                acc2 = MFMA16(A, *(const short8*)(wb + 32*128 + k0),   acc2, 0,0,0); \
                acc3 = MFMA16(A, *(const short8*)(wb + 48*128 + k0),   acc3, 0,0,0); }
            KSTEP(a0, 0) KSTEP(a1, 32) KSTEP(a2, 64) KSTEP(a3, 96)
            #undef KSTEP

            const int which = (cb * 64) >> 7;   // 0=Q 1=K 2=V
            #define STORE_CT(CT, ACC) { \
                const int c  = (cb * 64 + CT * 16) & 127; \
                const int h  = c >> 4; \
                const int bh = bb * 8 + h; \
                const int dd = i16; \
                if (which == 0) { \
                    u16* p = qws + ((size_t)(bh * N_ + n)) * 16 + dd; \
                    p[0]  = f2bf(ACC[0] * SCALE_L2E); p[16] = f2bf(ACC[1] * SCALE_L2E); \
                    p[32] = f2bf(ACC[2] * SCALE_L2E); p[48] = f2bf(ACC[3] * SCALE_L2E); \
                } else if (which == 1) { \
                    u16* p = kws2 + ((size_t)(bh * N_ + n)) * 32 + dd; \
                    p[0]  = f2bf(ACC[0]); p[32] = f2bf(ACC[1]); \
                    p[64] = f2bf(ACC[2]); p[96] = f2bf(ACC[3]); \
                    if (dd == 0) { \
                        _Pragma("unroll") \
                        for (int r = 0; r < 4; r++) { \
                            const int nr = n + r; \
                            const bool valid = (nr == 0) || \
                                (maskp[nr - 1] != 0.0f && mapsp[bb * (N_ - 1) + nr - 1] != 0.0f); \
                            kws2[((size_t)(bh * N_ + nr)) * 32 + 16] = valid ? (u16)0 : BF_NINF; \
                        } \
                    } \
                } else { \
                    *(ushort4*)(vtws + ((size_t)(bh * 16 + dd)) * N_ + n) = \
                        make_ushort4(f2bf(ACC[0]), f2bf(ACC[1]), f2bf(ACC[2]), f2bf(ACC[3])); \
                } }
            STORE_CT(0, acc0)
            STORE_CT(1, acc1)
            STORE_CT(2, acc2)
            STORE_CT(3, acc3)
            #undef STORE_CT
        }
    }
    grid.sync();

    // ---------- P2: attention ----------
    {
        const int bh = blk >> 2;            // 0..127
        const int qb = blk & 3;             // 0..3
        const int bb = bh >> 3, h = bh & 7;
        const int qrow0 = qb * 256 + wave * 64;
        const int perm = ((i16 & 12) << 1) | (i16 & 3);

        const short8 zero8 = {0,0,0,0,0,0,0,0};
        const short8 ones8 = {BF_ONE,BF_ONE,BF_ONE,BF_ONE,BF_ONE,BF_ONE,BF_ONE,BF_ONE};

        short8 qf0 = zero8, qf1 = zero8, qf2 = zero8, qf3 = zero8;
        if (lane < 32) {
            const u16* qp = qws + ((size_t)(bh * N_ + qrow0 + i16)) * 16 + quad * 8;
            qf0 = *(const short8*)(qp);
            qf1 = *(const short8*)(qp + 256);
            qf2 = *(const short8*)(qp + 512);
            qf3 = *(const short8*)(qp + 768);
        } else if (lane < 48) {
            qf0[0] = BF_ONE; qf1[0] = BF_ONE; qf2[0] = BF_ONE; qf3[0] = BF_ONE;
        }

        const u16* kpA = kws2 + ((size_t)(bh * N_ + perm)) * 32 + quad * 8;
        const u16* kpB = kpA + 4 * 32;
        const u16* vp  = vtws + ((size_t)(bh * 16 + i16)) * N_ + quad * 8;

        f32x4 o0 = {0,0,0,0}, o1 = {0,0,0,0}, o2 = {0,0,0,0}, o3 = {0,0,0,0};
        f32x4 l0 = {0,0,0,0}, l1 = {0,0,0,0}, l2 = {0,0,0,0}, l3 = {0,0,0,0};
        const f32x4 zc = {0.f, 0.f, 0.f, 0.f};

        #pragma unroll 2
        for (int j0 = 0; j0 < N_; j0 += 32) {
            const short8 kfA = *(const short8*)kpA;
            const short8 kfB = *(const short8*)kpB;
            const short8 vf  = *(const short8*)vp;
            kpA += 32 * 32; kpB += 32 * 32; vp += 32;

            #define TILE(QF, O, L) { \
                f32x4 stA = MFMA16(kfA, QF, zc, 0, 0, 0); \
                f32x4 stB = MFMA16(kfB, QF, zc, 0, 0, 0); \
                float pA0 = __builtin_amdgcn_exp2f(stA[0]); \
                float pA1 = __builtin_amdgcn_exp2f(stA[1]); \
                float pA2 = __builtin_amdgcn_exp2f(stA[2]); \
                float pA3 = __builtin_amdgcn_exp2f(stA[3]); \
                float pB0 = __builtin_amdgcn_exp2f(stB[0]); \
                float pB1 = __builtin_amdgcn_exp2f(stB[1]); \
                float pB2 = __builtin_amdgcn_exp2f(stB[2]); \
                float pB3 = __builtin_amdgcn_exp2f(stB[3]); \
                frag8 pk; \
                pk.w[0] = pack2bf(pA0, pA1); pk.w[1] = pack2bf(pA2, pA3); \
                pk.w[2] = pack2bf(pB0, pB1); pk.w[3] = pack2bf(pB2, pB3); \
                O = MFMA16(vf,    pk.s, O, 0, 0, 0); \
                L = MFMA16(ones8, pk.s, L, 0, 0, 0); }
            TILE(qf0, o0, l0)
            TILE(qf1, o1, l1)
            TILE(qf2, o2, l2)
            TILE(qf3, o3, l3)
            #undef TILE
        }

        #define OUT_T(T, O, L) { \
            const float inv = 1.0f / L[0]; \
            ushort4 pko = make_ushort4(f2bf(O[0] * inv), f2bf(O[1] * inv), \
                                       f2bf(O[2] * inv), f2bf(O[3] * inv)); \
            *(ushort4*)(attnw + ((size_t)(bb * N_ + qrow0 + T * 16 + i16)) * DIM_ \
                        + h * 16 + quad * 4) = pko; }
        OUT_T(0, o0, l0)
        OUT_T(1, o1, l1)
        OUT_T(2, o2, l2)
        OUT_T(3, o3, l3)
        #undef OUT_T
    }
    grid.sync();

    // ---------- P3: out projection ----------
    {
        const int cb = blk & 1;
        const int rb = blk >> 1;
        const int row_m = rb * 64 + wave * 16;

        const u16* ap = attnw + (size_t)(row_m + i16) * 128;
        const u16* wb = woutb + (size_t)(cb * 64 + i16) * 128;

        f32x4 acc0 = {0,0,0,0}, acc1 = {0,0,0,0}, acc2 = {0,0,0,0}, acc3 = {0,0,0,0};

        #pragma unroll
        for (int ks = 0; ks < 4; ks++) {
            const int k0 = ks * 32 + quad * 8;
            const short8 a = *(const short8*)(ap + k0);
            acc0 = MFMA16(a, *(const short8*)(wb + k0),          acc0, 0, 0, 0);
            acc1 = MFMA16(a, *(const short8*)(wb + 16*128 + k0), acc1, 0, 0, 0);
            acc2 = MFMA16(a, *(const short8*)(wb + 32*128 + k0), acc2, 0, 0, 0);
            acc3 = MFMA16(a, *(const short8*)(wb + 48*128 + k0), acc3, 0, 0, 0);
        }

        const int row = row_m + quad * 4;
        #define STORE_CT(CT, ACC) { \
            const int col = cb * 64 + CT * 16 + i16; \
            const float bo = boutp[col]; \
            float* op = outp + (size_t)row * 128 + col; \
            op[0 * 128] = ACC[0] + bo; \
            op[1 * 128] = ACC[1] + bo; \
            op[2 * 128] = ACC[2] + bo; \
            op[3 * 128] = ACC[3] + bo; }
        STORE_CT(0, acc0)
        STORE_CT(1, acc1)
        STORE_CT(2, acc2)
        STORE_CT(3, acc3)
        #undef STORE_CT
    }
}

// ==================== Fallback path (exact R10 pipeline) ====================
__global__ __launch_bounds__(256) void prep_kernel(
    const float* __restrict__ x, const float* __restrict__ Wqkv,
    const float* __restrict__ Wout,
    u16* __restrict__ xb, u16* __restrict__ wqkvb, u16* __restrict__ woutb)
{
    const int b = blockIdx.x, tid = threadIdx.x;
    if (b < 2048) {
        const int i = b * 256 + tid;
        float4 v = ((const float4*)x)[i];
        ushort4 o = make_ushort4(f2bf(v.x), f2bf(v.y), f2bf(v.z), f2bf(v.w));
        *(ushort4*)(xb + (size_t)i * 4) = o;
    } else {
        const int t = (b - 2048) * 256 + tid;
        if (t < 49152) {
            const int k = t / 384, col = t - k * 384;
            wqkvb[(size_t)col * 128 + k] = f2bf(Wqkv[t]);
        } else {
            const int t2 = t - 49152;
            const int k = t2 >> 7, col = t2 & 127;
            woutb[(size_t)col * 128 + k] = f2bf(Wout[t2]);
        }
    }
}

__global__ __launch_bounds__(256) void qkv_kernel(
    const u16* __restrict__ xb, const u16* __restrict__ wqkvb,
    const float* __restrict__ maskp, const float* __restrict__ mapsp,
    u16* __restrict__ qws, u16* __restrict__ kws2, u16* __restrict__ vtws)
{
    const int tid  = threadIdx.x;
    const int wave = tid >> 6, lane = tid & 63;
    const int i16  = lane & 15, quad = lane >> 4;
    const int cb   = blockIdx.x % 6;
    const int rb   = blockIdx.x / 6;
    const int row_m = rb * 64 + wave * 16;

    const u16* xp = xb + (size_t)(row_m + i16) * 128;
    const u16* wb = wqkvb + (size_t)(cb * 64 + i16) * 128;

    f32x4 acc0 = {0,0,0,0}, acc1 = {0,0,0,0}, acc2 = {0,0,0,0}, acc3 = {0,0,0,0};

    #pragma unroll
    for (int ks = 0; ks < 4; ks++) {
        const int k0 = ks * 32 + quad * 8;
        const short8 a = *(const short8*)(xp + k0);
        acc0 = MFMA16(a, *(const short8*)(wb + k0),          acc0, 0, 0, 0);
        acc1 = MFMA16(a, *(const short8*)(wb + 16*128 + k0), acc1, 0, 0, 0);
        acc2 = MFMA16(a, *(const short8*)(wb + 32*128 + k0), acc2, 0, 0, 0);
        acc3 = MFMA16(a, *(const short8*)(wb + 48*128 + k0), acc3, 0, 0, 0);
    }

    const int which = (cb * 64) >> 7;
    const int row   = row_m + quad * 4;
    const int bb    = row >> 10, n = row & 1023;

    #define STORE_CT(CT, ACC) { \
        const int c  = (cb * 64 + CT * 16) & 127; \
        const int h  = c >> 4; \
        const int bh = bb * 8 + h; \
        const int dd = i16; \
        if (which == 0) { \
            u16* p = qws + ((size_t)(bh * N_ + n)) * 16 + dd; \
            p[0]  = f2bf(ACC[0] * SCALE_L2E); p[16] = f2bf(ACC[1] * SCALE_L2E); \
            p[32] = f2bf(ACC[2] * SCALE_L2E); p[48] = f2bf(ACC[3] * SCALE_L2E); \
        } else if (which == 1) { \
            u16* p = kws2 + ((size_t)(bh * N_ + n)) * 32 + dd; \
            p[0]  = f2bf(ACC[0]); p[32] = f2bf(ACC[1]); \
            p[64] = f2bf(ACC[2]); p[96] = f2bf(ACC[3]); \
            if (dd == 0) { \
                _Pragma("unroll") \
                for (int r = 0; r < 4; r++) { \
                    const int nr = n + r; \
                    const bool valid = (nr == 0) || \
                        (maskp[nr - 1] != 0.0f && mapsp[bb * (N_ - 1) + nr - 1] != 0.0f); \
                    kws2[((size_t)(bh * N_ + nr)) * 32 + 16] = valid ? (u16)0 : BF_NINF; \
                } \
            } \
        } else { \
            *(ushort4*)(vtws + ((size_t)(bh * 16 + dd)) * N_ + n) = \
                make_ushort4(f2bf(ACC[0]), f2bf(ACC[1]), f2bf(ACC[2]), f2bf(ACC[3])); \
        } }
    STORE_CT(0, acc0)
    STORE_CT(1, acc1)
    STORE_CT(2, acc2)
    STORE_CT(3, acc3)
    #undef STORE_CT
}

__global__ __launch_bounds__(256) void attn_kernel(
    const u16* __restrict__ qws, const u16* __restrict__ kws2, const u16* __restrict__ vtws,
    u16* __restrict__ attn)
{
    const int tid  = threadIdx.x;
    const int wave = tid >> 6, lane = tid & 63;
    const int i16  = lane & 15, quad = lane >> 4;
    const int bh   = blockIdx.x;
    const int qb   = blockIdx.y;
    const int bb   = bh >> 3, h = bh & 7;
    const int qrow0 = qb * 256 + wave * 64;
    const int perm = ((i16 & 12) << 1) | (i16 & 3);

    const short8 zero8 = {0,0,0,0,0,0,0,0};
    const short8 ones8 = {BF_ONE,BF_ONE,BF_ONE,BF_ONE,BF_ONE,BF_ONE,BF_ONE,BF_ONE};

    short8 qf0 = zero8, qf1 = zero8, qf2 = zero8, qf3 = zero8;
    if (lane < 32) {
        const u16* qp = qws + ((size_t)(bh * N_ + qrow0 + i16)) * 16 + quad * 8;
        qf0 = *(const short8*)(qp);
        qf1 = *(const short8*)(qp + 256);
        qf2 = *(const short8*)(qp + 512);
        qf3 = *(const short8*)(qp + 768);
    } else if (lane < 48) {
        qf0[0] = BF_ONE; qf1[0] = BF_ONE; qf2[0] = BF_ONE; qf3[0] = BF_ONE;
    }

    const u16* kpA = kws2 + ((size_t)(bh * N_ + perm)) * 32 + quad * 8;
    const u16* kpB = kpA + 4 * 32;
    const u16* vp  = vtws + ((size_t)(bh * 16 + i16)) * N_ + quad * 8;

    f32x4 o0 = {0,0,0,0}, o1 = {0,0,0,0}, o2 = {0,0,0,0}, o3 = {0,0,0,0};
    f32x4 l0 = {0,0,0,0}, l1 = {0,0,0,0}, l2 = {0,0,0,0}, l3 = {0,0,0,0};
    const f32x4 zc = {0.f, 0.f, 0.f, 0.f};

    #pragma unroll 2
    for (int j0 = 0; j0 < N_; j0 += 32) {
        const short8 kfA = *(const short8*)kpA;
        const short8 kfB = *(const short8*)kpB;
        const short8 vf  = *(const short8*)vp;
        kpA += 32 * 32; kpB += 32 * 32; vp += 32;

        #define TILE(QF, O, L) { \
            f32x4 stA = MFMA16(kfA, QF, zc, 0, 0, 0); \
            f32x4 stB = MFMA16(kfB, QF, zc, 0, 0, 0); \
            float pA0 = __builtin_amdgcn_exp2f(stA[0]); \
            float pA1 = __builtin_amdgcn_exp2f(stA[1]); \
            float pA2 = __builtin_amdgcn_exp2f(stA[2]); \
            float pA3 = __builtin_amdgcn_exp2f(stA[3]); \
            float pB0 = __builtin_amdgcn_exp2f(stB[0]); \
            float pB1 = __builtin_amdgcn_exp2f(stB[1]); \
            float pB2 = __builtin_amdgcn_exp2f(stB[2]); \
            float pB3 = __builtin_amdgcn_exp2f(stB[3]); \
            frag8 pk; \
            pk.w[0] = pack2bf(pA0, pA1); pk.w[1] = pack2bf(pA2, pA3); \
            pk.w[2] = pack2bf(pB0, pB1); pk.w[3] = pack2bf(pB2, pB3); \
            O = MFMA16(vf,    pk.s, O, 0, 0, 0); \
            L = MFMA16(ones8, pk.s, L, 0, 0, 0); }
        TILE(qf0, o0, l0)
        TILE(qf1, o1, l1)
        TILE(qf2, o2, l2)
        TILE(qf3, o3, l3)
        #undef TILE
    }

    #define OUT_T(T, O, L) { \
        const float inv = 1.0f / L[0]; \
        ushort4 pko = make_ushort4(f2bf(O[0] * inv), f2bf(O[1] * inv), \
                                   f2bf(O[2] * inv), f2bf(O[3] * inv)); \
        *(ushort4*)(attn + ((size_t)(bb * N_ + qrow0 + T * 16 + i16)) * DIM_ \
                    + h * 16 + quad * 4) = pko; }
    OUT_T(0, o0, l0)
    OUT_T(1, o1, l1)
    OUT_T(2, o2, l2)
    OUT_T(3, o3, l3)
    #undef OUT_T
}

__global__ __launch_bounds__(256) void out_kernel(
    const u16* __restrict__ attnw, const u16* __restrict__ woutb,
    const float* __restrict__ boutp, float* __restrict__ outp)
{
    const int tid  = threadIdx.x;
    const int wave = tid >> 6, lane = tid & 63;
    const int i16  = lane & 15, quad = lane >> 4;
    const int cb   = blockIdx.x & 1;
    const int rb   = blockIdx.x >> 1;
    const int row_m = rb * 64 + wave * 16;

    const u16* ap = attnw + (size_t)(row_m + i16) * 128;
    const u16* wb = woutb + (size_t)(cb * 64 + i16) * 128;

    f32x4 acc0 = {0,0,0,0}, acc1 = {0,0,0,0}, acc2 = {0,0,0,0}, acc3 = {0,0,0,0};

    #pragma unroll
    for (int ks = 0; ks < 4; ks++) {
        const int k0 = ks * 32 + quad * 8;
        const short8 a = *(const short8*)(ap + k0);
        acc0 = MFMA16(a, *(const short8*)(wb + k0),          acc0, 0, 0, 0);
        acc1 = MFMA16(a, *(const short8*)(wb + 16*128 + k0), acc1, 0, 0, 0);
        acc2 = MFMA16(a, *(const short8*)(wb + 32*128 + k0), acc2, 0, 0, 0);
        acc3 = MFMA16(a, *(const short8*)(wb + 48*128 + k0), acc3, 0, 0, 0);
    }

    const int row = row_m + quad * 4;
    #define STORE_CT(CT, ACC) { \
        const int col = cb * 64 + CT * 16 + i16; \
        const float bo = boutp[col]; \
        float* op = outp + (size_t)row * 128 + col; \
        op[0 * 128] = ACC[0] + bo; \
        op[1 * 128] = ACC[1] + bo; \
        op[2 * 128] = ACC[2] + bo; \
        op[3 * 128] = ACC[3] + bo; }
    STORE_CT(0, acc0)
    STORE_CT(1, acc1)
    STORE_CT(2, acc2)
    STORE_CT(3, acc3)
    #undef STORE_CT
}

extern "C" void kernel_launch(void* const* d_in, const int* in_sizes, int n_in,
                              void* d_out, int out_size, void* d_ws, size_t ws_size,
                              hipStream_t stream) {
    const float* x    = (const float*)d_in[0];
    const float* mask = (const float*)d_in[1];
    const float* maps = (const float*)d_in[2];
    const float* Wqkv = (const float*)d_in[3];
    const float* Wout = (const float*)d_in[4];
    const float* bout = (const float*)d_in[5];
    // ws (u16 units): Q 2M | K2 4M | Vt 2M | attn 2M | Wqkvb 48K | Woutb 16K | xb 2M (fallback)
    u16* qws    = (u16*)d_ws;
    u16* kws2   = qws   + (size_t)2 * 1024 * 1024;
    u16* vtws   = kws2  + (size_t)4 * 1024 * 1024;
    u16* attnw  = vtws  + (size_t)2 * 1024 * 1024;
    u16* wqkvb  = attnw + (size_t)2 * 1024 * 1024;
    u16* woutb  = wqkvb + (size_t)384 * 128;
    u16* xbws   = woutb + (size_t)128 * 128;
    float* outp = (float*)d_out;

    void* args[] = { (void*)&x, (void*)&mask, (void*)&maps, (void*)&Wqkv,
                     (void*)&Wout, (void*)&bout, (void*)&qws, (void*)&kws2,
                     (void*)&vtws, (void*)&attnw, (void*)&wqkvb, (void*)&woutb,
                     (void*)&outp };
    hipError_t err = hipLaunchCooperativeKernel(
        reinterpret_cast<const void*>(fused_kernel),
        dim3(512), dim3(256), args, 0, stream);

    if (err != hipSuccess) {
        // Fallback: R10 4-kernel pipeline
        prep_kernel<<<dim3(2304), dim3(256), 0, stream>>>(x, Wqkv, Wout, xbws, wqkvb, woutb);
        qkv_kernel<<<dim3(1536), dim3(256), 0, stream>>>(xbws, wqkvb, mask, maps, qws, kws2, vtws);
        attn_kernel<<<dim3(128, 4), dim3(256), 0, stream>>>(qws, kws2, vtws, attnw);
        out_kernel<<<dim3(512), dim3(256), 0, stream>>>(attnw, woutb, bout, outp);
    }
}

// Round 12
// 129.049 us; speedup vs baseline: 2.2595x; 2.2595x over previous
//
#include <hip/hip_runtime.h>
#include <math.h>

#define B_   16
#define N_   1024
#define DIM_ 128
#define H_   8
#define D_   16
#define BH_  128

typedef unsigned short u16;
typedef unsigned int   u32;
typedef __attribute__((ext_vector_type(8))) short short8;
typedef __attribute__((ext_vector_type(4))) float f32x4;

__device__ __forceinline__ u16 f2bf(float f) {
    union { float f; u32 i; } c; c.f = f;
    u32 r = c.i + 0x7FFFu + ((c.i >> 16) & 1u);
    return (u16)(r >> 16);
}
// pack two f32 -> packed bf16 pair (round-half-up)
__device__ __forceinline__ u32 pack2bf(float a, float b) {
    union { float f; u32 i; } ca, cb; ca.f = a; cb.f = b;
    return ((ca.i + 0x8000u) >> 16) | ((cb.i + 0x8000u) & 0xFFFF0000u);
}
union frag8 { short8 s; u32 w[4]; };

#define BF_ONE  ((short)0x3F80)
#define BF_NINF ((u16)0xFF80)
#define SCALE_L2E (0.08838834764831845f * 1.4426950408889634f)
#define MFMA16 __builtin_amdgcn_mfma_f32_16x16x32_bf16

// ---------------- Kernel 1: qkv = x @ Wqkv, bf16 MFMA, conversions in-register.
// A-frags: f32 x rows -> bf16 (2 float4 loads + 4 packs), loaded once per wave.
// B-frags: f32 Wqkv [k][col] -> 8 strided loads (stride 384 f) + 4 packs.
// No prep kernel, no xb/wqkvb round-trip (R11 lesson: dispatches cost ~5-10 us,
// grid.sync costs ~55 us -- fewer dispatches, no cooperative fusion).
// K rows widened to 32 bf16: slots 0-15 = K, slot 16 = mask bias (0/-inf, log2
// domain), 17-31 don't-care. Q pre-scaled by SCALE_L2E.
__global__ __launch_bounds__(256) void qkv_kernel(
    const float* __restrict__ x, const float* __restrict__ Wqkv,
    const float* __restrict__ maskp, const float* __restrict__ mapsp,
    u16* __restrict__ qws, u16* __restrict__ kws2, u16* __restrict__ vtws)
{
    const int tid  = threadIdx.x;
    const int wave = tid >> 6, lane = tid & 63;
    const int i16  = lane & 15, quad = lane >> 4;
    const int cb   = blockIdx.x % 6;          // 64-col block
    const int rb   = blockIdx.x / 6;          // 64-row block
    const int row_m = rb * 64 + wave * 16;

    const float* xp = x + (size_t)(row_m + i16) * 128;

    // A-frags for all 4 k-steps, converted in-register
    short8 a0, a1, a2, a3;
    #define LOADA(A, K0) { \
        const int k0 = (K0) + quad * 8; \
        const float4 xa = *(const float4*)(xp + k0); \
        const float4 xb2 = *(const float4*)(xp + k0 + 4); \
        frag8 t_; \
        t_.w[0] = pack2bf(xa.x, xa.y);  t_.w[1] = pack2bf(xa.z, xa.w); \
        t_.w[2] = pack2bf(xb2.x, xb2.y); t_.w[3] = pack2bf(xb2.z, xb2.w); \
        A = t_.s; }
    LOADA(a0, 0) LOADA(a1, 32) LOADA(a2, 64) LOADA(a3, 96)
    #undef LOADA

    f32x4 acc0 = {0,0,0,0}, acc1 = {0,0,0,0}, acc2 = {0,0,0,0}, acc3 = {0,0,0,0};

    #define KSTEP(A, K0) { \
        const int k0 = (K0) + quad * 8; \
        const float* wk = Wqkv + (size_t)k0 * 384 + cb * 64 + i16; \
        _Pragma("unroll") \
        for (int ct = 0; ct < 4; ct++) { \
            const float* wp = wk + ct * 16; \
            const float w0 = wp[0*384], w1 = wp[1*384], w2 = wp[2*384], w3 = wp[3*384]; \
            const float w4 = wp[4*384], w5 = wp[5*384], w6 = wp[6*384], w7 = wp[7*384]; \
            frag8 b_; \
            b_.w[0] = pack2bf(w0, w1); b_.w[1] = pack2bf(w2, w3); \
            b_.w[2] = pack2bf(w4, w5); b_.w[3] = pack2bf(w6, w7); \
            if      (ct == 0) acc0 = MFMA16(A, b_.s, acc0, 0, 0, 0); \
            else if (ct == 1) acc1 = MFMA16(A, b_.s, acc1, 0, 0, 0); \
            else if (ct == 2) acc2 = MFMA16(A, b_.s, acc2, 0, 0, 0); \
            else              acc3 = MFMA16(A, b_.s, acc3, 0, 0, 0); \
        } }
    KSTEP(a0, 0) KSTEP(a1, 32) KSTEP(a2, 64) KSTEP(a3, 96)
    #undef KSTEP

    // Epilogue. C/D layout: col = i16 (n-index), row = quad*4 + r.
    const int which = (cb * 64) >> 7;   // 0=Q 1=K 2=V
    const int row   = row_m + quad * 4;
    const int bb    = row >> 10, n = row & 1023;

    #define STORE_CT(CT, ACC) { \
        const int c  = (cb * 64 + CT * 16) & 127; \
        const int h  = c >> 4; \
        const int bh = bb * 8 + h; \
        const int dd = i16; \
        if (which == 0) { \
            u16* p = qws + ((size_t)(bh * N_ + n)) * 16 + dd; \
            p[0]  = f2bf(ACC[0] * SCALE_L2E); p[16] = f2bf(ACC[1] * SCALE_L2E); \
            p[32] = f2bf(ACC[2] * SCALE_L2E); p[48] = f2bf(ACC[3] * SCALE_L2E); \
        } else if (which == 1) { \
            u16* p = kws2 + ((size_t)(bh * N_ + n)) * 32 + dd; \
            p[0]  = f2bf(ACC[0]); p[32] = f2bf(ACC[1]); \
            p[64] = f2bf(ACC[2]); p[96] = f2bf(ACC[3]); \
            if (dd == 0) { \
                _Pragma("unroll") \
                for (int r = 0; r < 4; r++) { \
                    const int nr = n + r; \
                    const bool valid = (nr == 0) || \
                        (maskp[nr - 1] != 0.0f && mapsp[bb * (N_ - 1) + nr - 1] != 0.0f); \
                    kws2[((size_t)(bh * N_ + nr)) * 32 + 16] = valid ? (u16)0 : BF_NINF; \
                } \
            } \
        } else { \
            *(ushort4*)(vtws + ((size_t)(bh * 16 + dd)) * N_ + n) = \
                make_ushort4(f2bf(ACC[0]), f2bf(ACC[1]), f2bf(ACC[2]), f2bf(ACC[3])); \
        } }
    STORE_CT(0, acc0)
    STORE_CT(1, acc1)
    STORE_CT(2, acc2)
    STORE_CT(3, acc3)
    #undef STORE_CT
}

// ---------------- Kernel 2: attention (R9/R10 proven structure, unchanged).
// 4 q-tiles/wave, bias-in-K (slot 16 via quad2 B-lane = 1.0), no-max exp2
// softmax, j-permuted S^T -> P^T B-frag is the lane's own registers.
__global__ __launch_bounds__(256) void attn_kernel(
    const u16* __restrict__ qws, const u16* __restrict__ kws2, const u16* __restrict__ vtws,
    u16* __restrict__ attn)
{
    const int tid  = threadIdx.x;
    const int wave = tid >> 6, lane = tid & 63;
    const int i16  = lane & 15, quad = lane >> 4;
    const int bh   = blockIdx.x;            // 0..127
    const int qb   = blockIdx.y;            // 0..3
    const int bb   = bh >> 3, h = bh & 7;
    const int qrow0 = qb * 256 + wave * 64;
    const int perm = ((i16 & 12) << 1) | (i16 & 3);

    const short8 zero8 = {0,0,0,0,0,0,0,0};
    const short8 ones8 = {BF_ONE,BF_ONE,BF_ONE,BF_ONE,BF_ONE,BF_ONE,BF_ONE,BF_ONE};

    short8 qf0 = zero8, qf1 = zero8, qf2 = zero8, qf3 = zero8;
    if (lane < 32) {
        const u16* qp = qws + ((size_t)(bh * N_ + qrow0 + i16)) * 16 + quad * 8;
        qf0 = *(const short8*)(qp);
        qf1 = *(const short8*)(qp + 256);
        qf2 = *(const short8*)(qp + 512);
        qf3 = *(const short8*)(qp + 768);
    } else if (lane < 48) {
        qf0[0] = BF_ONE; qf1[0] = BF_ONE; qf2[0] = BF_ONE; qf3[0] = BF_ONE;
    }

    const u16* kpA = kws2 + ((size_t)(bh * N_ + perm)) * 32 + quad * 8;
    const u16* kpB = kpA + 4 * 32;
    const u16* vp  = vtws + ((size_t)(bh * 16 + i16)) * N_ + quad * 8;

    f32x4 o0 = {0,0,0,0}, o1 = {0,0,0,0}, o2 = {0,0,0,0}, o3 = {0,0,0,0};
    f32x4 l0 = {0,0,0,0}, l1 = {0,0,0,0}, l2 = {0,0,0,0}, l3 = {0,0,0,0};
    const f32x4 zc = {0.f, 0.f, 0.f, 0.f};

    #pragma unroll 2
    for (int j0 = 0; j0 < N_; j0 += 32) {
        const short8 kfA = *(const short8*)kpA;
        const short8 kfB = *(const short8*)kpB;
        const short8 vf  = *(const short8*)vp;
        kpA += 32 * 32; kpB += 32 * 32; vp += 32;

        #define TILE(QF, O, L) { \
            f32x4 stA = MFMA16(kfA, QF, zc, 0, 0, 0); \
            f32x4 stB = MFMA16(kfB, QF, zc, 0, 0, 0); \
            float pA0 = __builtin_amdgcn_exp2f(stA[0]); \
            float pA1 = __builtin_amdgcn_exp2f(stA[1]); \
            float pA2 = __builtin_amdgcn_exp2f(stA[2]); \
            float pA3 = __builtin_amdgcn_exp2f(stA[3]); \
            float pB0 = __builtin_amdgcn_exp2f(stB[0]); \
            float pB1 = __builtin_amdgcn_exp2f(stB[1]); \
            float pB2 = __builtin_amdgcn_exp2f(stB[2]); \
            float pB3 = __builtin_amdgcn_exp2f(stB[3]); \
            frag8 pk; \
            pk.w[0] = pack2bf(pA0, pA1); pk.w[1] = pack2bf(pA2, pA3); \
            pk.w[2] = pack2bf(pB0, pB1); pk.w[3] = pack2bf(pB2, pB3); \
            O = MFMA16(vf,    pk.s, O, 0, 0, 0); \
            L = MFMA16(ones8, pk.s, L, 0, 0, 0); }
        TILE(qf0, o0, l0)
        TILE(qf1, o1, l1)
        TILE(qf2, o2, l2)
        TILE(qf3, o3, l3)
        #undef TILE
    }

    #define OUT_T(T, O, L) { \
        const float inv = 1.0f / L[0]; \
        ushort4 pko = make_ushort4(f2bf(O[0] * inv), f2bf(O[1] * inv), \
                                   f2bf(O[2] * inv), f2bf(O[3] * inv)); \
        *(ushort4*)(attn + ((size_t)(bb * N_ + qrow0 + T * 16 + i16)) * DIM_ \
                    + h * 16 + quad * 4) = pko; }
    OUT_T(0, o0, l0)
    OUT_T(1, o1, l1)
    OUT_T(2, o2, l2)
    OUT_T(3, o3, l3)
    #undef OUT_T
}

// ---------------- Kernel 3: out = attn @ Wout + bout, B-frags direct from f32.
__global__ __launch_bounds__(256) void out_kernel(
    const u16* __restrict__ attnw, const float* __restrict__ Wout,
    const float* __restrict__ boutp, float* __restrict__ outp)
{
    const int tid  = threadIdx.x;
    const int wave = tid >> 6, lane = tid & 63;
    const int i16  = lane & 15, quad = lane >> 4;
    const int cb   = blockIdx.x & 1;
    const int rb   = blockIdx.x >> 1;
    const int row_m = rb * 64 + wave * 16;

    const u16* ap = attnw + (size_t)(row_m + i16) * 128;

    f32x4 acc0 = {0,0,0,0}, acc1 = {0,0,0,0}, acc2 = {0,0,0,0}, acc3 = {0,0,0,0};

    #pragma unroll
    for (int ks = 0; ks < 4; ks++) {
        const int k0 = ks * 32 + quad * 8;
        const short8 a = *(const short8*)(ap + k0);
        const float* wk = Wout + (size_t)k0 * 128 + cb * 64 + i16;
        #pragma unroll
        for (int ct = 0; ct < 4; ct++) {
            const float* wp = wk + ct * 16;
            const float w0 = wp[0*128], w1 = wp[1*128], w2 = wp[2*128], w3 = wp[3*128];
            const float w4 = wp[4*128], w5 = wp[5*128], w6 = wp[6*128], w7 = wp[7*128];
            frag8 b_;
            b_.w[0] = pack2bf(w0, w1); b_.w[1] = pack2bf(w2, w3);
            b_.w[2] = pack2bf(w4, w5); b_.w[3] = pack2bf(w6, w7);
            if      (ct == 0) acc0 = MFMA16(a, b_.s, acc0, 0, 0, 0);
            else if (ct == 1) acc1 = MFMA16(a, b_.s, acc1, 0, 0, 0);
            else if (ct == 2) acc2 = MFMA16(a, b_.s, acc2, 0, 0, 0);
            else              acc3 = MFMA16(a, b_.s, acc3, 0, 0, 0);
        }
    }

    const int row = row_m + quad * 4;
    #define STORE_CT(CT, ACC) { \
        const int col = cb * 64 + CT * 16 + i16; \
        const float bo = boutp[col]; \
        float* op = outp + (size_t)row * 128 + col; \
        op[0 * 128] = ACC[0] + bo; \
        op[1 * 128] = ACC[1] + bo; \
        op[2 * 128] = ACC[2] + bo; \
        op[3 * 128] = ACC[3] + bo; }
    STORE_CT(0, acc0)
    STORE_CT(1, acc1)
    STORE_CT(2, acc2)
    STORE_CT(3, acc3)
    #undef STORE_CT
}

extern "C" void kernel_launch(void* const* d_in, const int* in_sizes, int n_in,
                              void* d_out, int out_size, void* d_ws, size_t ws_size,
                              hipStream_t stream) {
    const float* x    = (const float*)d_in[0];
    const float* mask = (const float*)d_in[1];
    const float* maps = (const float*)d_in[2];
    const float* Wqkv = (const float*)d_in[3];
    const float* Wout = (const float*)d_in[4];
    const float* bout = (const float*)d_in[5];
    // ws (u16 units): Q 2M | K2 4M | Vt 2M | attn 2M = 20 MB
    u16* qws   = (u16*)d_ws;
    u16* kws2  = qws  + (size_t)2 * 1024 * 1024;
    u16* vtws  = kws2 + (size_t)4 * 1024 * 1024;
    u16* attnw = vtws + (size_t)2 * 1024 * 1024;

    qkv_kernel<<<dim3(1536), dim3(256), 0, stream>>>(x, Wqkv, mask, maps, qws, kws2, vtws);
    attn_kernel<<<dim3(128, 4), dim3(256), 0, stream>>>(qws, kws2, vtws, attnw);
    out_kernel<<<dim3(512), dim3(256), 0, stream>>>(attnw, Wout, bout, (float*)d_out);
}

// Round 13
// 120.621 us; speedup vs baseline: 2.4173x; 1.0699x over previous
//
#include <hip/hip_runtime.h>
#include <math.h>

#define B_   16
#define N_   1024
#define DIM_ 128
#define H_   8
#define D_   16
#define BH_  128

typedef unsigned short u16;
typedef unsigned int   u32;
typedef __attribute__((ext_vector_type(8))) short short8;
typedef __attribute__((ext_vector_type(4))) float f32x4;

__device__ __forceinline__ u16 f2bf(float f) {
    union { float f; u32 i; } c; c.f = f;
    u32 r = c.i + 0x7FFFu + ((c.i >> 16) & 1u);
    return (u16)(r >> 16);
}
// pack two f32 -> packed bf16 pair (round-half-up)
__device__ __forceinline__ u32 pack2bf(float a, float b) {
    union { float f; u32 i; } ca, cb; ca.f = a; cb.f = b;
    return ((ca.i + 0x8000u) >> 16) | ((cb.i + 0x8000u) & 0xFFFF0000u);
}
union frag8 { short8 s; u32 w[4]; };

#define BF_ONE  ((short)0x3F80)
#define BF_NINF ((u16)0xFF80)
#define SCALE_L2E (0.08838834764831845f * 1.4426950408889634f)
#define MFMA16 __builtin_amdgcn_mfma_f32_16x16x32_bf16

// LDS weight tile: [col][k], row stride 136 u16 (16B-aligned rows: 136*2=272,
// k0 multiple of 8 -> b128 reads aligned; bank start (4c+k/2)%32 -> 2-way = free).
#define WSTRIDE 136

// ---------------- Kernel 1: qkv = x @ Wqkv, bf16 MFMA.
// Grid 512 = 256 row-blocks x 2 halves; each block does 64 rows x 192 cols
// (3 col-blocks) -> x re-read 2x (was 6x). Weight tiles LDS-staged with
// COALESCED f32 reads (R12 lesson: per-lane strided weight loads are the
// qkv bottleneck; R10/R12 A/B showed contiguous B-frags worth ~a dispatch).
// K rows widened to 32 bf16: slots 0-15 = K, slot 16 = mask bias (0/-inf,
// log2 domain), 17-31 don't-care. Q pre-scaled by SCALE_L2E.
__global__ __launch_bounds__(256) void qkv_kernel(
    const float* __restrict__ x, const float* __restrict__ Wqkv,
    const float* __restrict__ maskp, const float* __restrict__ mapsp,
    u16* __restrict__ qws, u16* __restrict__ kws2, u16* __restrict__ vtws)
{
    __shared__ u16 wlds[3 * 64 * WSTRIDE];   // 52.2 KB
    const int tid  = threadIdx.x;
    const int wave = tid >> 6, lane = tid & 63;
    const int i16  = lane & 15, quad = lane >> 4;
    const int half = blockIdx.x & 1;          // col halves {0..2} / {3..5}
    const int rb   = blockIdx.x >> 1;         // 64-row block
    const int row_m = rb * 64 + wave * 16;
    const int colbase0 = half * 192;

    // ---- stage 3 weight tiles: coalesced f32 reads, bf16 pack, ds_write_b32
    {
        const int col = tid & 63, pg = tid >> 6;   // pg 0..3
        for (int ci = 0; ci < 3; ci++) {
            const float* wsrc = Wqkv + colbase0 + ci * 64 + col;
            u16* dst = wlds + ci * (64 * WSTRIDE) + col * WSTRIDE;
            #pragma unroll
            for (int it = 0; it < 16; it++) {
                const int p = it * 4 + pg;         // k-pair index 0..63
                const float v0 = wsrc[(size_t)(2 * p)     * 384];
                const float v1 = wsrc[(size_t)(2 * p + 1) * 384];
                *(u32*)(dst + 2 * p) = pack2bf(v0, v1);
            }
        }
    }

    // ---- A-frags (x rows f32 -> bf16 in-register), issued before the barrier
    const float* xp = x + (size_t)(row_m + i16) * 128;
    short8 a0, a1, a2, a3;
    #define LOADA(A, K0) { \
        const int k0 = (K0) + quad * 8; \
        const float4 xa = *(const float4*)(xp + k0); \
        const float4 xb2 = *(const float4*)(xp + k0 + 4); \
        frag8 t_; \
        t_.w[0] = pack2bf(xa.x, xa.y);  t_.w[1] = pack2bf(xa.z, xa.w); \
        t_.w[2] = pack2bf(xb2.x, xb2.y); t_.w[3] = pack2bf(xb2.z, xb2.w); \
        A = t_.s; }
    LOADA(a0, 0) LOADA(a1, 32) LOADA(a2, 64) LOADA(a3, 96)
    #undef LOADA

    __syncthreads();

    const int row = row_m + quad * 4;
    const int bb  = row >> 10, n = row & 1023;

    #pragma unroll 1
    for (int ci = 0; ci < 3; ci++) {
        const int cb = half * 3 + ci;
        const u16* wt = wlds + ci * (64 * WSTRIDE);
        f32x4 acc0 = {0,0,0,0}, acc1 = {0,0,0,0}, acc2 = {0,0,0,0}, acc3 = {0,0,0,0};

        #define KSTEP(A, K0) { \
            const int k0 = (K0) + quad * 8; \
            acc0 = MFMA16(A, *(const short8*)(wt + (0*16 + i16) * WSTRIDE + k0), acc0, 0,0,0); \
            acc1 = MFMA16(A, *(const short8*)(wt + (1*16 + i16) * WSTRIDE + k0), acc1, 0,0,0); \
            acc2 = MFMA16(A, *(const short8*)(wt + (2*16 + i16) * WSTRIDE + k0), acc2, 0,0,0); \
            acc3 = MFMA16(A, *(const short8*)(wt + (3*16 + i16) * WSTRIDE + k0), acc3, 0,0,0); }
        KSTEP(a0, 0) KSTEP(a1, 32) KSTEP(a2, 64) KSTEP(a3, 96)
        #undef KSTEP

        const int which = (cb * 64) >> 7;   // 0=Q 1=K 2=V (uniform per ci)
        #define STORE_CT(CT, ACC) { \
            const int c  = (cb * 64 + CT * 16) & 127; \
            const int h  = c >> 4; \
            const int bh = bb * 8 + h; \
            const int dd = i16; \
            if (which == 0) { \
                u16* p = qws + ((size_t)(bh * N_ + n)) * 16 + dd; \
                p[0]  = f2bf(ACC[0] * SCALE_L2E); p[16] = f2bf(ACC[1] * SCALE_L2E); \
                p[32] = f2bf(ACC[2] * SCALE_L2E); p[48] = f2bf(ACC[3] * SCALE_L2E); \
            } else if (which == 1) { \
                u16* p = kws2 + ((size_t)(bh * N_ + n)) * 32 + dd; \
                p[0]  = f2bf(ACC[0]); p[32] = f2bf(ACC[1]); \
                p[64] = f2bf(ACC[2]); p[96] = f2bf(ACC[3]); \
                if (dd == 0) { \
                    _Pragma("unroll") \
                    for (int r = 0; r < 4; r++) { \
                        const int nr = n + r; \
                        const bool valid = (nr == 0) || \
                            (maskp[nr - 1] != 0.0f && mapsp[bb * (N_ - 1) + nr - 1] != 0.0f); \
                        kws2[((size_t)(bh * N_ + nr)) * 32 + 16] = valid ? (u16)0 : BF_NINF; \
                    } \
                } \
            } else { \
                *(ushort4*)(vtws + ((size_t)(bh * 16 + dd)) * N_ + n) = \
                    make_ushort4(f2bf(ACC[0]), f2bf(ACC[1]), f2bf(ACC[2]), f2bf(ACC[3])); \
            } }
        STORE_CT(0, acc0)
        STORE_CT(1, acc1)
        STORE_CT(2, acc2)
        STORE_CT(3, acc3)
        #undef STORE_CT
    }
}

// ---------------- Kernel 2: attention (R9-R12 proven structure, unchanged).
// 4 q-tiles/wave, bias-in-K (slot 16 via quad2 B-lane = 1.0), no-max exp2
// softmax, j-permuted S^T -> P^T B-frag is the lane's own registers.
__global__ __launch_bounds__(256) void attn_kernel(
    const u16* __restrict__ qws, const u16* __restrict__ kws2, const u16* __restrict__ vtws,
    u16* __restrict__ attn)
{
    const int tid  = threadIdx.x;
    const int wave = tid >> 6, lane = tid & 63;
    const int i16  = lane & 15, quad = lane >> 4;
    const int bh   = blockIdx.x;            // 0..127
    const int qb   = blockIdx.y;            // 0..3
    const int bb   = bh >> 3, h = bh & 7;
    const int qrow0 = qb * 256 + wave * 64;
    const int perm = ((i16 & 12) << 1) | (i16 & 3);

    const short8 zero8 = {0,0,0,0,0,0,0,0};
    const short8 ones8 = {BF_ONE,BF_ONE,BF_ONE,BF_ONE,BF_ONE,BF_ONE,BF_ONE,BF_ONE};

    short8 qf0 = zero8, qf1 = zero8, qf2 = zero8, qf3 = zero8;
    if (lane < 32) {
        const u16* qp = qws + ((size_t)(bh * N_ + qrow0 + i16)) * 16 + quad * 8;
        qf0 = *(const short8*)(qp);
        qf1 = *(const short8*)(qp + 256);
        qf2 = *(const short8*)(qp + 512);
        qf3 = *(const short8*)(qp + 768);
    } else if (lane < 48) {
        qf0[0] = BF_ONE; qf1[0] = BF_ONE; qf2[0] = BF_ONE; qf3[0] = BF_ONE;
    }

    const u16* kpA = kws2 + ((size_t)(bh * N_ + perm)) * 32 + quad * 8;
    const u16* kpB = kpA + 4 * 32;
    const u16* vp  = vtws + ((size_t)(bh * 16 + i16)) * N_ + quad * 8;

    f32x4 o0 = {0,0,0,0}, o1 = {0,0,0,0}, o2 = {0,0,0,0}, o3 = {0,0,0,0};
    f32x4 l0 = {0,0,0,0}, l1 = {0,0,0,0}, l2 = {0,0,0,0}, l3 = {0,0,0,0};
    const f32x4 zc = {0.f, 0.f, 0.f, 0.f};

    #pragma unroll 2
    for (int j0 = 0; j0 < N_; j0 += 32) {
        const short8 kfA = *(const short8*)kpA;
        const short8 kfB = *(const short8*)kpB;
        const short8 vf  = *(const short8*)vp;
        kpA += 32 * 32; kpB += 32 * 32; vp += 32;

        #define TILE(QF, O, L) { \
            f32x4 stA = MFMA16(kfA, QF, zc, 0, 0, 0); \
            f32x4 stB = MFMA16(kfB, QF, zc, 0, 0, 0); \
            float pA0 = __builtin_amdgcn_exp2f(stA[0]); \
            float pA1 = __builtin_amdgcn_exp2f(stA[1]); \
            float pA2 = __builtin_amdgcn_exp2f(stA[2]); \
            float pA3 = __builtin_amdgcn_exp2f(stA[3]); \
            float pB0 = __builtin_amdgcn_exp2f(stB[0]); \
            float pB1 = __builtin_amdgcn_exp2f(stB[1]); \
            float pB2 = __builtin_amdgcn_exp2f(stB[2]); \
            float pB3 = __builtin_amdgcn_exp2f(stB[3]); \
            frag8 pk; \
            pk.w[0] = pack2bf(pA0, pA1); pk.w[1] = pack2bf(pA2, pA3); \
            pk.w[2] = pack2bf(pB0, pB1); pk.w[3] = pack2bf(pB2, pB3); \
            O = MFMA16(vf,    pk.s, O, 0, 0, 0); \
            L = MFMA16(ones8, pk.s, L, 0, 0, 0); }
        TILE(qf0, o0, l0)
        TILE(qf1, o1, l1)
        TILE(qf2, o2, l2)
        TILE(qf3, o3, l3)
        #undef TILE
    }

    #define OUT_T(T, O, L) { \
        const float inv = 1.0f / L[0]; \
        ushort4 pko = make_ushort4(f2bf(O[0] * inv), f2bf(O[1] * inv), \
                                   f2bf(O[2] * inv), f2bf(O[3] * inv)); \
        *(ushort4*)(attn + ((size_t)(bb * N_ + qrow0 + T * 16 + i16)) * DIM_ \
                    + h * 16 + quad * 4) = pko; }
    OUT_T(0, o0, l0)
    OUT_T(1, o1, l1)
    OUT_T(2, o2, l2)
    OUT_T(3, o3, l3)
    #undef OUT_T
}

// ---------------- Kernel 3: out = attn @ Wout + bout; Wout tile LDS-staged.
__global__ __launch_bounds__(256) void out_kernel(
    const u16* __restrict__ attnw, const float* __restrict__ Wout,
    const float* __restrict__ boutp, float* __restrict__ outp)
{
    __shared__ u16 wlds[64 * WSTRIDE];   // 17.4 KB
    const int tid  = threadIdx.x;
    const int wave = tid >> 6, lane = tid & 63;
    const int i16  = lane & 15, quad = lane >> 4;
    const int cb   = blockIdx.x & 1;
    const int rb   = blockIdx.x >> 1;
    const int row_m = rb * 64 + wave * 16;

    {   // stage Wout cols [cb*64, +64), all 128 k (coalesced)
        const int col = tid & 63, pg = tid >> 6;
        const float* wsrc = Wout + cb * 64 + col;
        u16* dst = wlds + col * WSTRIDE;
        #pragma unroll
        for (int it = 0; it < 16; it++) {
            const int p = it * 4 + pg;
            const float v0 = wsrc[(size_t)(2 * p)     * 128];
            const float v1 = wsrc[(size_t)(2 * p + 1) * 128];
            *(u32*)(dst + 2 * p) = pack2bf(v0, v1);
        }
    }

    const u16* ap = attnw + (size_t)(row_m + i16) * 128;
    // A-frags before barrier
    short8 a0 = *(const short8*)(ap + quad * 8);
    short8 a1 = *(const short8*)(ap + 32 + quad * 8);
    short8 a2 = *(const short8*)(ap + 64 + quad * 8);
    short8 a3 = *(const short8*)(ap + 96 + quad * 8);

    __syncthreads();

    f32x4 acc0 = {0,0,0,0}, acc1 = {0,0,0,0}, acc2 = {0,0,0,0}, acc3 = {0,0,0,0};
    #define KSTEP(A, K0) { \
        const int k0 = (K0) + quad * 8; \
        acc0 = MFMA16(A, *(const short8*)(wlds + (0*16 + i16) * WSTRIDE + k0), acc0, 0,0,0); \
        acc1 = MFMA16(A, *(const short8*)(wlds + (1*16 + i16) * WSTRIDE + k0), acc1, 0,0,0); \
        acc2 = MFMA16(A, *(const short8*)(wlds + (2*16 + i16) * WSTRIDE + k0), acc2, 0,0,0); \
        acc3 = MFMA16(A, *(const short8*)(wlds + (3*16 + i16) * WSTRIDE + k0), acc3, 0,0,0); }
    KSTEP(a0, 0) KSTEP(a1, 32) KSTEP(a2, 64) KSTEP(a3, 96)
    #undef KSTEP

    const int row = row_m + quad * 4;
    #define STORE_CT(CT, ACC) { \
        const int col = cb * 64 + CT * 16 + i16; \
        const float bo = boutp[col]; \
        float* op = outp + (size_t)row * 128 + col; \
        op[0 * 128] = ACC[0] + bo; \
        op[1 * 128] = ACC[1] + bo; \
        op[2 * 128] = ACC[2] + bo; \
        op[3 * 128] = ACC[3] + bo; }
    STORE_CT(0, acc0)
    STORE_CT(1, acc1)
    STORE_CT(2, acc2)
    STORE_CT(3, acc3)
    #undef STORE_CT
}

extern "C" void kernel_launch(void* const* d_in, const int* in_sizes, int n_in,
                              void* d_out, int out_size, void* d_ws, size_t ws_size,
                              hipStream_t stream) {
    const float* x    = (const float*)d_in[0];
    const float* mask = (const float*)d_in[1];
    const float* maps = (const float*)d_in[2];
    const float* Wqkv = (const float*)d_in[3];
    const float* Wout = (const float*)d_in[4];
    const float* bout = (const float*)d_in[5];
    // ws (u16 units): Q 2M | K2 4M | Vt 2M | attn 2M = 20 MB
    u16* qws   = (u16*)d_ws;
    u16* kws2  = qws  + (size_t)2 * 1024 * 1024;
    u16* vtws  = kws2 + (size_t)4 * 1024 * 1024;
    u16* attnw = vtws + (size_t)2 * 1024 * 1024;

    qkv_kernel<<<dim3(512), dim3(256), 0, stream>>>(x, Wqkv, mask, maps, qws, kws2, vtws);
    attn_kernel<<<dim3(128, 4), dim3(256), 0, stream>>>(qws, kws2, vtws, attnw);
    out_kernel<<<dim3(512), dim3(256), 0, stream>>>(attnw, Wout, bout, (float*)d_out);
}